// Round 10
// baseline (90.433 us; speedup 1.0000x reference)
//
#include <hip/hip_runtime.h>
#include <hip/hip_bf16.h>

// ---------- types ----------
typedef __attribute__((ext_vector_type(8))) short    short8;
typedef __attribute__((ext_vector_type(4))) float    f32x4;
typedef __attribute__((ext_vector_type(4))) _Float16 f16x4;
typedef __attribute__((ext_vector_type(2))) unsigned u32x2;

#define NCLS 10
#define TILE 64            // rows per tile (2 k-slices of 32)
#define TPB  512           // 8 waves; 2 blocks/CU
#define NQ   10            // upper-triangular 16x16 quads of 64x64 Gram
#define PPB  (NCLS * NQ * 256)   // halves per block of partials
#define CH   16            // reduction chunks

#define AS1 __attribute__((address_space(1)))
#define AS3 __attribute__((address_space(3)))

#define MF(a, b, c) __builtin_amdgcn_mfma_f32_16x16x32_bf16((a), (b), (c), 0, 0, 0)

static __device__ __forceinline__ unsigned pkh2(float a, float b) {
    unsigned short ha = __builtin_bit_cast(unsigned short, (_Float16)a);
    unsigned short hb = __builtin_bit_cast(unsigned short, (_Float16)b);
    return (unsigned)ha | ((unsigned)hb << 16);
}

// ---------- compute one tile: own class (10 quads) + extra-class slice ----------
// All LDS read addresses: per-thread base regs + compile-time immediates.
static __device__ __forceinline__ void compute_tile(
        const char* hsb, const char* mkb, int cls, int xcls, int wq,
        int hi, int col, f32x4 (&acc)[NQ], f32x4 (&accx)[3]) {
    const int s56 = (col & 3) << 4;        // swizzle bits 4-5
    const int s6  = (col & 4) << 4;        // swizzle bit 6 (0 or 64)
    const char* rb0 = hsb + col * 128 + ((hi * 16) ^ s56) + s6;         // ks=0
    const char* rb1 = hsb + col * 128 + ((hi * 16) ^ s56) + (64 ^ s6);  // ks=1
    const char* mb  = mkb + cls  * 128 + hi * 16;
    const char* xb  = mkb + xcls * 128 + hi * 16;

#pragma unroll
    for (int ks = 0; ks < 2; ++ks) {
        const char* rb = ks ? rb1 : rb0;
        const short8 m = *(const short8*)(mb + ks * 64);
        short8 raw[4], am[4];
#pragma unroll
        for (int nb = 0; nb < 4; ++nb) {
            raw[nb] = *(const short8*)(rb + nb * 2048);   // ds_read_b128 offset:
            am[nb]  = raw[nb] & m;
        }
        acc[0] = MF(am[0], am[0], acc[0]);
        acc[1] = MF(am[0], am[1], acc[1]);
        acc[2] = MF(am[0], am[2], acc[2]);
        acc[3] = MF(am[0], am[3], acc[3]);
        acc[4] = MF(am[1], am[1], acc[4]);
        acc[5] = MF(am[1], am[2], acc[5]);
        acc[6] = MF(am[1], am[3], acc[6]);
        acc[7] = MF(am[2], am[2], acc[7]);
        acc[8] = MF(am[2], am[3], acc[8]);
        acc[9] = MF(am[3], am[3], acc[9]);

        const short8 mx = *(const short8*)(xb + ks * 64);
        switch (wq) {
        case 0: { short8 x0 = raw[0] & mx, x1 = raw[1] & mx;
                  accx[0] = MF(x0, x0, accx[0]);
                  accx[1] = MF(x0, x1, accx[1]);
                  accx[2] = MF(x1, x1, accx[2]); } break;
        case 1: { short8 x0 = raw[0] & mx, x2 = raw[2] & mx, x3 = raw[3] & mx;
                  accx[0] = MF(x0, x2, accx[0]);
                  accx[1] = MF(x0, x3, accx[1]); } break;
        case 2: { short8 x1 = raw[1] & mx, x2 = raw[2] & mx, x3 = raw[3] & mx;
                  accx[0] = MF(x1, x2, accx[0]);
                  accx[1] = MF(x1, x3, accx[1]);
                  accx[2] = MF(x2, x2, accx[2]); } break;
        default:{ short8 x2 = raw[2] & mx, x3 = raw[3] & mx;
                  accx[0] = MF(x2, x3, accx[0]);
                  accx[1] = MF(x3, x3, accx[1]); } break;
        }
    }
}

// ---------- kernel 1: masked Grams; phase = {issue k+1, convert k || compute k-1} ----------
// partials: [G][NCLS][NQ][256] f16; cntp: [G][16] int. Both fully overwritten.
__global__ __launch_bounds__(TPB, 4) void HL_gram(
        const float* __restrict__ h, const int* __restrict__ yhat,
        _Float16* __restrict__ partials, int* __restrict__ cntp,
        int N, int ntiles, int G) {
    __shared__ __align__(16) float          fs[2][TILE * 64];    // 32 KB fp32
    __shared__ __align__(16) unsigned short hs[2][64 * TILE];    // 16 KB bf16 swz
    __shared__ __align__(16) unsigned short mk[2][NCLS * TILE];  // 2.5 KB masks
    __shared__ __align__(16) int            ylds[2][TILE];       // 512 B

    const int tid  = threadIdx.x;
    const int wid  = tid >> 6;      // 0..7; wave owns class wid
    const int lane = tid & 63;
    const int hi   = lane >> 4;
    const int col  = lane & 15;

    const int cls  = wid;
    const int xcls = 8 + (wid >> 2);
    const int wq   = wid & 3;

    f32x4 acc[NQ], accx[3];
#pragma unroll
    for (int q = 0; q < NQ; ++q) acc[q] = (f32x4){0.f, 0.f, 0.f, 0.f};
#pragma unroll
    for (int q = 0; q < 3; ++q)  accx[q] = (f32x4){0.f, 0.f, 0.f, 0.f};
    int c0=0,c1=0,c2=0,c3=0,c4=0,c5=0,c6=0,c7=0,c8=0,c9=0;   // wave-7 counts

    const int bid = blockIdx.x;
    const int K   = (ntiles - bid + G - 1) / G;

    // ---- 32-bit additive DMA source offsets (bytes into h / yhat) ----
    const unsigned step   = (unsigned)G * TILE * 256u;          // h bytes/phase
    const unsigned maxoff = (unsigned)(N - 1) * 256u + (unsigned)(tid & 15) * 16u;
    unsigned off0 = ((unsigned)bid * TILE + (unsigned)(tid >> 4)) * 256u
                    + (unsigned)(tid & 15) * 16u;               // chunk tid
    // chunk tid+512 is off0 + 8192 (same col bytes, +32 rows)
    const unsigned ystep  = (unsigned)G * TILE * 4u;
    const unsigned maxy   = (unsigned)(N - 4) * 4u;
    unsigned offy = (unsigned)bid * 256u + (unsigned)lane * 16u;   // wave 7, lane<16
    int rowN = bid * TILE + lane;                                   // wave-7 row id

    // wave-uniform LDS destinations for the DMA
    char* fdst0 = (char*)&fs[0][0] + wid * 1024;
    char* fdst1 = (char*)&fs[1][0] + wid * 1024;

    // ---- prologue: DMA tile 0 into slot 0 ----
    {
        unsigned o0 = off0 > maxoff ? maxoff : off0;
        unsigned o1 = off0 + 8192u; o1 = o1 > maxoff ? maxoff : o1;
        __builtin_amdgcn_global_load_lds((const AS1 float*)((const char*)h + o0),
                                         (AS3 float*)fdst0, 16, 0, 0);
        __builtin_amdgcn_global_load_lds((const AS1 float*)((const char*)h + o1),
                                         (AS3 float*)(fdst0 + 8192), 16, 0, 0);
        if (wid == 7 && lane < 16) {
            unsigned oy = offy > maxy ? maxy : offy;
            __builtin_amdgcn_global_load_lds((const AS1 int*)((const char*)yhat + oy),
                                             (AS3 int*)&ylds[0][0], 16, 0, 0);
        }
        off0 += step; offy += ystep;
    }

    for (int k = 0; k < K; ++k) {
        const int slot = k & 1;

        // ---- entry: tile k's DMA drained (1 phase of flight); phase k-1 LDS visible
        asm volatile("s_waitcnt vmcnt(0)" ::: "memory");
        asm volatile("s_waitcnt lgkmcnt(0)" ::: "memory");
        __builtin_amdgcn_s_barrier();
        __builtin_amdgcn_sched_barrier(0);

        // ---- issue DMA for tile k+1 into the other slot ----
        if (k + 1 < K) {
            char* fd = slot ? fdst0 : fdst1;
            unsigned o0 = off0 > maxoff ? maxoff : off0;
            unsigned o1 = off0 + 8192u; o1 = o1 > maxoff ? maxoff : o1;
            __builtin_amdgcn_global_load_lds((const AS1 float*)((const char*)h + o0),
                                             (AS3 float*)fd, 16, 0, 0);
            __builtin_amdgcn_global_load_lds((const AS1 float*)((const char*)h + o1),
                                             (AS3 float*)(fd + 8192), 16, 0, 0);
            if (wid == 7 && lane < 16) {
                unsigned oy = offy > maxy ? maxy : offy;
                __builtin_amdgcn_global_load_lds((const AS1 int*)((const char*)yhat + oy),
                                                 (AS3 int*)&ylds[slot ^ 1][0], 16, 0, 0);
            }
            off0 += step; offy += ystep;
        }

        // ---- convert(k) and compute(k-1), per-wave order flipped for pipe mixing
        const float* fsb = &fs[slot][0];
        const char*  hsw = (const char*)&hs[slot][0];
        const char*  hsr = (const char*)&hs[slot ^ 1][0];
        const char*  mkw = (const char*)&mk[slot][0];
        const char*  mkr = (const char*)&mk[slot ^ 1][0];

        if (wid & 1) {
            // ---------- convert first ----------
            {
                const float* fp = fsb + (wid * 8) * 64 + lane;
                float x[8];
#pragma unroll
                for (int j = 0; j < 8; ++j) x[j] = fp[j * 64];
                u32x2 lo, hi2;
                lo[0]  = pkh2(0,0); // placeholder overwritten below
                unsigned w0, w1, w2, w3;
                {
                    __hip_bfloat162 p0 = __float22bfloat162_rn(make_float2(x[0], x[1]));
                    __hip_bfloat162 p1 = __float22bfloat162_rn(make_float2(x[2], x[3]));
                    __hip_bfloat162 p2 = __float22bfloat162_rn(make_float2(x[4], x[5]));
                    __hip_bfloat162 p3 = __float22bfloat162_rn(make_float2(x[6], x[7]));
                    __builtin_memcpy(&w0, &p0, 4); __builtin_memcpy(&w1, &p1, 4);
                    __builtin_memcpy(&w2, &p2, 4); __builtin_memcpy(&w3, &p3, 4);
                }
                lo[0] = w0; lo[1] = w1; hi2[0] = w2; hi2[1] = w3;
                char* hb = (char*)hsw + lane * 128 + ((wid * 16) ^ ((lane & 7) << 4));
                *(u32x2*)hb       = lo;
                *(u32x2*)(hb + 8) = hi2;
            }
            if (wid == 7) {
                int y = ylds[slot][lane];
                if (rowN >= N) y = -1;
                unsigned short* mbw = (unsigned short*)mkw;
#pragma unroll
                for (int c = 0; c < NCLS; ++c)
                    mbw[c * TILE + lane] = (y == c) ? (unsigned short)0xFFFFu
                                                    : (unsigned short)0u;
                c0 += (int)__popcll(__ballot(y == 0));
                c1 += (int)__popcll(__ballot(y == 1));
                c2 += (int)__popcll(__ballot(y == 2));
                c3 += (int)__popcll(__ballot(y == 3));
                c4 += (int)__popcll(__ballot(y == 4));
                c5 += (int)__popcll(__ballot(y == 5));
                c6 += (int)__popcll(__ballot(y == 6));
                c7 += (int)__popcll(__ballot(y == 7));
                c8 += (int)__popcll(__ballot(y == 8));
                c9 += (int)__popcll(__ballot(y == 9));
                rowN += G * TILE;
            }
            if (k > 0)
                compute_tile(hsr, mkr, cls, xcls, wq, hi, col, acc, accx);
        } else {
            // ---------- compute first ----------
            if (k > 0)
                compute_tile(hsr, mkr, cls, xcls, wq, hi, col, acc, accx);
            {
                const float* fp = fsb + (wid * 8) * 64 + lane;
                float x[8];
#pragma unroll
                for (int j = 0; j < 8; ++j) x[j] = fp[j * 64];
                unsigned w0, w1, w2, w3;
                {
                    __hip_bfloat162 p0 = __float22bfloat162_rn(make_float2(x[0], x[1]));
                    __hip_bfloat162 p1 = __float22bfloat162_rn(make_float2(x[2], x[3]));
                    __hip_bfloat162 p2 = __float22bfloat162_rn(make_float2(x[4], x[5]));
                    __hip_bfloat162 p3 = __float22bfloat162_rn(make_float2(x[6], x[7]));
                    __builtin_memcpy(&w0, &p0, 4); __builtin_memcpy(&w1, &p1, 4);
                    __builtin_memcpy(&w2, &p2, 4); __builtin_memcpy(&w3, &p3, 4);
                }
                u32x2 lo, hi2;
                lo[0] = w0; lo[1] = w1; hi2[0] = w2; hi2[1] = w3;
                char* hb = (char*)hsw + lane * 128 + ((wid * 16) ^ ((lane & 7) << 4));
                *(u32x2*)hb       = lo;
                *(u32x2*)(hb + 8) = hi2;
            }
        }
    }

    // ---- epilogue: compute the last converted tile ----
    asm volatile("s_waitcnt lgkmcnt(0)" ::: "memory");
    __builtin_amdgcn_s_barrier();
    __builtin_amdgcn_sched_barrier(0);
    compute_tile((const char*)&hs[(K - 1) & 1][0], (const char*)&mk[(K - 1) & 1][0],
                 cls, xcls, wq, hi, col, acc, accx);

    // ---- stream partials (f16) + per-block counts ----
    _Float16* pb = partials + (size_t)bid * PPB;
    {
        _Float16* po = pb + (size_t)cls * (NQ * 256);
#pragma unroll
        for (int q = 0; q < NQ; ++q) {
            u32x2 pk; pk[0] = pkh2(acc[q][0], acc[q][1]);
            pk[1] = pkh2(acc[q][2], acc[q][3]);
            *(u32x2*)(po + q * 256 + (lane << 2)) = pk;
        }
    }
    {
        _Float16* px = pb + (size_t)xcls * (NQ * 256) + (lane << 2);
        u32x2 pk0, pk1, pk2;
        pk0[0] = pkh2(accx[0][0], accx[0][1]); pk0[1] = pkh2(accx[0][2], accx[0][3]);
        pk1[0] = pkh2(accx[1][0], accx[1][1]); pk1[1] = pkh2(accx[1][2], accx[1][3]);
        pk2[0] = pkh2(accx[2][0], accx[2][1]); pk2[1] = pkh2(accx[2][2], accx[2][3]);
        switch (wq) {
        case 0: *(u32x2*)(px + 0 * 256) = pk0;
                *(u32x2*)(px + 1 * 256) = pk1;
                *(u32x2*)(px + 4 * 256) = pk2; break;
        case 1: *(u32x2*)(px + 2 * 256) = pk0;
                *(u32x2*)(px + 3 * 256) = pk1; break;
        case 2: *(u32x2*)(px + 5 * 256) = pk0;
                *(u32x2*)(px + 6 * 256) = pk1;
                *(u32x2*)(px + 7 * 256) = pk2; break;
        default:*(u32x2*)(px + 8 * 256) = pk0;
                *(u32x2*)(px + 9 * 256) = pk1; break;
        }
    }
    if (wid == 7 && lane == 0) {
        int* cp = cntp + bid * 16;
        cp[0]=c0; cp[1]=c1; cp[2]=c2; cp[3]=c3; cp[4]=c4;
        cp[5]=c5; cp[6]=c6; cp[7]=c7; cp[8]=c8; cp[9]=c9;
    }
}

// ---------- kernel 2: chunked block-reduction of f16 partials (atomic-free) ----------
__global__ void HL_reduce(const _Float16* __restrict__ partials, float* __restrict__ rpart,
                          float* __restrict__ out, int G, int CS) {
    const int idx = blockIdx.x * blockDim.x + threadIdx.x;
    if (blockIdx.x == 0 && threadIdx.x == 0) out[0] = 0.f;
    if (idx >= CH * NCLS * NQ * 64) return;
    const int ch = idx / (NCLS * NQ * 64);
    const int r  = idx % (NCLS * NQ * 64);
    const int cq = r >> 6;
    const int l  = r & 63;

    int b0 = ch * CS;
    int b1 = b0 + CS; if (b1 > G) b1 = G;

    f32x4 s = (f32x4){0.f, 0.f, 0.f, 0.f};
    const _Float16* p = partials + (size_t)cq * 256 + (l << 2);
    for (int b = b0; b < b1; ++b) {
        f16x4 v = *(const f16x4*)(p + (size_t)b * PPB);
        s[0] += (float)v[0]; s[1] += (float)v[1];
        s[2] += (float)v[2]; s[3] += (float)v[3];
    }
    *reinterpret_cast<f32x4*>(rpart + ((size_t)ch * (NCLS * NQ) + cq) * 256 + (l << 2)) = s;
}

// ---------- kernel 3: counts + M = 0.5*G/cnt + I; loss += 0.5*logdet ----------
__global__ __launch_bounds__(64, 1) void HL_chol(
        const float* __restrict__ rpart, const int* __restrict__ cntp,
        float* __restrict__ out, int G) {
    __shared__ float M[64][68];
    __shared__ float lcol[64];
    const int cls = blockIdx.x;
    const int i   = threadIdx.x;   // lane 0..63

    int c = 0;
    for (int b = i; b < G; b += 64) c += cntp[b * 16 + cls];
#pragma unroll
    for (int off = 32; off > 0; off >>= 1) c += __shfl_xor(c, off);
    const float inv = 0.5f / (float)c;

    const int QMB[NQ] = {0,0,0,0,1,1,1,2,2,3};
    const int QNB[NQ] = {0,1,2,3,1,2,3,2,3,3};
    const float* rp = rpart + (size_t)cls * (NQ * 256);
#pragma unroll
    for (int q = 0; q < NQ; ++q) {
        f32x4 s = (f32x4){0.f, 0.f, 0.f, 0.f};
#pragma unroll
        for (int ch = 0; ch < CH; ++ch)
            s += *reinterpret_cast<const f32x4*>(rp + (size_t)ch * (NCLS * NQ * 256) + q * 256 + (i << 2));
        const int row0 = QMB[q] * 16 + ((i >> 4) << 2);
        const int colo = QNB[q] * 16 + (i & 15);
#pragma unroll
        for (int rr = 0; rr < 4; ++rr) {
            M[row0 + rr][colo] = s[rr];
            M[colo][row0 + rr] = s[rr];
        }
    }
    __syncthreads();

    float row[64];
#pragma unroll
    for (int c2 = 0; c2 < 64; ++c2)
        row[c2] = M[i][c2] * inv + (c2 == i ? 1.0f : 0.0f);

#pragma unroll
    for (int j = 0; j < 64; ++j) {
        const float piv = __shfl(row[j], j);
        const float li  = row[j] * rsqrtf(piv);
        lcol[i] = li;
        __syncthreads();
#pragma unroll
        for (int c2 = j + 1; c2 < 64; ++c2)
            row[c2] -= li * lcol[c2];
        __syncthreads();
    }

    float slog = 0.f;
#pragma unroll
    for (int j = 0; j < 64; ++j)
        if (i == j) slog = __logf(row[j]);
    slog += __shfl_down(slog, 32); slog += __shfl_down(slog, 16);
    slog += __shfl_down(slog, 8);  slog += __shfl_down(slog, 4);
    slog += __shfl_down(slog, 2);  slog += __shfl_down(slog, 1);
    if (i == 0) atomicAdd(out, 0.5f * slog);
}

// ---------- launcher ----------
extern "C" void kernel_launch(void* const* d_in, const int* in_sizes, int n_in,
                              void* d_out, int out_size, void* d_ws, size_t ws_size,
                              hipStream_t stream) {
    const float* h    = (const float*)d_in[0];
    const int*   yhat = (const int*)d_in[1];
    const int    N    = in_sizes[1];
    float* out = (float*)d_out;

    // ws layout: [rpart CH*100*256 f32][cntp G*16 int][partials G*PPB f16]
    const size_t rpart_sz = (size_t)CH * NCLS * NQ * 256 * sizeof(float);
    const size_t cntp_off = rpart_sz;

    const int ntiles = (N + TILE - 1) / TILE;
    int G = 512;    // 2 blocks per CU
    {
        const size_t perG = 64 + (size_t)PPB * sizeof(_Float16);
        if (ws_size > rpart_sz) {
            size_t maxG = (ws_size - rpart_sz) / perG;
            if ((size_t)G > maxG) G = (int)maxG;
        } else G = 1;
        if (G < 1) G = 1;
    }
    if (G > ntiles) G = ntiles;

    const size_t partials_off = cntp_off + (size_t)G * 16 * sizeof(int);
    float*    rpart    = (float*)d_ws;
    int*      cntp     = (int*)((char*)d_ws + cntp_off);
    _Float16* partials = (_Float16*)((char*)d_ws + partials_off);

    HL_gram<<<G, TPB, 0, stream>>>(h, yhat, partials, cntp, N, ntiles, G);

    int CS = (G + CH - 1) / CH;
    const int rthreads = CH * NCLS * NQ * 64;
    HL_reduce<<<(rthreads + 255) / 256, 256, 0, stream>>>(partials, rpart, out, G, CS);

    HL_chol<<<NCLS, 64, 0, stream>>>(rpart, cntp, out, G);
}

// Round 11
// 90.325 us; speedup vs baseline: 1.0012x; 1.0012x over previous
//
#include <hip/hip_runtime.h>
#include <hip/hip_bf16.h>

// ---------- types ----------
typedef __attribute__((ext_vector_type(8))) short    short8;
typedef __attribute__((ext_vector_type(4))) float    f32x4;
typedef __attribute__((ext_vector_type(4))) _Float16 f16x4;
typedef __attribute__((ext_vector_type(2))) unsigned u32x2;

#define NCLS 10
#define TILE 64            // rows per tile (2 k-slices of 32)
#define TPB  512           // 8 waves; 2 blocks/CU
#define NQ   10            // upper-triangular 16x16 quads of 64x64 Gram
#define PPB  (NCLS * NQ * 256)   // halves per block of partials
#define CH   16            // reduction chunks

#define AS1 __attribute__((address_space(1)))
#define AS3 __attribute__((address_space(3)))

#define MF(a, b, c) __builtin_amdgcn_mfma_f32_16x16x32_bf16((a), (b), (c), 0, 0, 0)

static __device__ __forceinline__ unsigned pkh2(float a, float b) {
    unsigned short ha = __builtin_bit_cast(unsigned short, (_Float16)a);
    unsigned short hb = __builtin_bit_cast(unsigned short, (_Float16)b);
    return (unsigned)ha | ((unsigned)hb << 16);
}

// ---------- compute one tile: own class (10 quads) + extra-class slice ----------
// All LDS read addresses: per-thread base regs + compile-time immediates.
static __device__ __forceinline__ void compute_tile(
        const char* hsb, const char* mkb, int cls, int xcls, int wq,
        int hi, int col, f32x4 (&acc)[NQ], f32x4 (&accx)[3]) {
    const int s56 = (col & 3) << 4;        // swizzle bits 4-5
    const int s6  = (col & 4) << 4;        // swizzle bit 6 (0 or 64)
    const char* rb0 = hsb + col * 128 + ((hi * 16) ^ s56) + s6;         // ks=0
    const char* rb1 = hsb + col * 128 + ((hi * 16) ^ s56) + (64 ^ s6);  // ks=1
    const char* mb  = mkb + cls  * 128 + hi * 16;
    const char* xb  = mkb + xcls * 128 + hi * 16;

#pragma unroll
    for (int ks = 0; ks < 2; ++ks) {
        const char* rb = ks ? rb1 : rb0;
        const short8 m = *(const short8*)(mb + ks * 64);
        short8 raw[4], am[4];
#pragma unroll
        for (int nb = 0; nb < 4; ++nb) {
            raw[nb] = *(const short8*)(rb + nb * 2048);   // ds_read_b128 offset:
            am[nb]  = raw[nb] & m;
        }
        acc[0] = MF(am[0], am[0], acc[0]);
        acc[1] = MF(am[0], am[1], acc[1]);
        acc[2] = MF(am[0], am[2], acc[2]);
        acc[3] = MF(am[0], am[3], acc[3]);
        acc[4] = MF(am[1], am[1], acc[4]);
        acc[5] = MF(am[1], am[2], acc[5]);
        acc[6] = MF(am[1], am[3], acc[6]);
        acc[7] = MF(am[2], am[2], acc[7]);
        acc[8] = MF(am[2], am[3], acc[8]);
        acc[9] = MF(am[3], am[3], acc[9]);

        const short8 mx = *(const short8*)(xb + ks * 64);
        switch (wq) {
        case 0: { short8 x0 = raw[0] & mx, x1 = raw[1] & mx;
                  accx[0] = MF(x0, x0, accx[0]);
                  accx[1] = MF(x0, x1, accx[1]);
                  accx[2] = MF(x1, x1, accx[2]); } break;
        case 1: { short8 x0 = raw[0] & mx, x2 = raw[2] & mx, x3 = raw[3] & mx;
                  accx[0] = MF(x0, x2, accx[0]);
                  accx[1] = MF(x0, x3, accx[1]); } break;
        case 2: { short8 x1 = raw[1] & mx, x2 = raw[2] & mx, x3 = raw[3] & mx;
                  accx[0] = MF(x1, x2, accx[0]);
                  accx[1] = MF(x1, x3, accx[1]);
                  accx[2] = MF(x2, x2, accx[2]); } break;
        default:{ short8 x2 = raw[2] & mx, x3 = raw[3] & mx;
                  accx[0] = MF(x2, x3, accx[0]);
                  accx[1] = MF(x3, x3, accx[1]); } break;
        }
    }
}

// ---------- kernel 1: masked Grams; phase = {issue k+1, convert k || compute k-1} ----------
// partials: [G][NCLS][NQ][256] f16; cntp: [G][16] int. Both fully overwritten.
__global__ __launch_bounds__(TPB, 4) void HL_gram(
        const float* __restrict__ h, const int* __restrict__ yhat,
        _Float16* __restrict__ partials, int* __restrict__ cntp,
        int N, int ntiles, int G) {
    __shared__ __align__(16) float          fs[2][TILE * 64];    // 32 KB fp32
    __shared__ __align__(16) unsigned short hs[2][64 * TILE];    // 16 KB bf16 swz
    __shared__ __align__(16) unsigned short mk[2][NCLS * TILE];  // 2.5 KB masks
    __shared__ __align__(16) int            ylds[2][TILE];       // 512 B

    const int tid  = threadIdx.x;
    const int wid  = tid >> 6;      // 0..7; wave owns class wid
    const int lane = tid & 63;
    const int hi   = lane >> 4;
    const int col  = lane & 15;

    const int cls  = wid;
    const int xcls = 8 + (wid >> 2);
    const int wq   = wid & 3;

    f32x4 acc[NQ], accx[3];
#pragma unroll
    for (int q = 0; q < NQ; ++q) acc[q] = (f32x4){0.f, 0.f, 0.f, 0.f};
#pragma unroll
    for (int q = 0; q < 3; ++q)  accx[q] = (f32x4){0.f, 0.f, 0.f, 0.f};
    int c0=0,c1=0,c2=0,c3=0,c4=0,c5=0,c6=0,c7=0,c8=0,c9=0;   // wave-7 counts

    const int bid = blockIdx.x;
    const int K   = (ntiles - bid + G - 1) / G;

    // ---- 32-bit additive DMA source offsets (bytes into h / yhat) ----
    const unsigned step   = (unsigned)G * TILE * 256u;          // h bytes/phase
    const unsigned maxoff = (unsigned)(N - 1) * 256u + (unsigned)(tid & 15) * 16u;
    unsigned off0 = ((unsigned)bid * TILE + (unsigned)(tid >> 4)) * 256u
                    + (unsigned)(tid & 15) * 16u;               // chunk tid
    // chunk tid+512 is off0 + 8192 (same col bytes, +32 rows)
    const unsigned ystep  = (unsigned)G * TILE * 4u;
    const unsigned maxy   = (unsigned)(N - 4) * 4u;
    unsigned offy = (unsigned)bid * 256u + (unsigned)lane * 16u;   // wave 7, lane<16
    int rowN = bid * TILE + lane;                                   // wave-7 row id

    // wave-uniform LDS destinations for the DMA
    char* fdst0 = (char*)&fs[0][0] + wid * 1024;
    char* fdst1 = (char*)&fs[1][0] + wid * 1024;

    // ---- prologue: DMA tile 0 into slot 0 ----
    {
        unsigned o0 = off0 > maxoff ? maxoff : off0;
        unsigned o1 = off0 + 8192u; o1 = o1 > maxoff ? maxoff : o1;
        __builtin_amdgcn_global_load_lds((const AS1 float*)((const char*)h + o0),
                                         (AS3 float*)fdst0, 16, 0, 0);
        __builtin_amdgcn_global_load_lds((const AS1 float*)((const char*)h + o1),
                                         (AS3 float*)(fdst0 + 8192), 16, 0, 0);
        if (wid == 7 && lane < 16) {
            unsigned oy = offy > maxy ? maxy : offy;
            __builtin_amdgcn_global_load_lds((const AS1 int*)((const char*)yhat + oy),
                                             (AS3 int*)&ylds[0][0], 16, 0, 0);
        }
        off0 += step; offy += ystep;
    }

    for (int k = 0; k < K; ++k) {
        const int slot = k & 1;

        // ---- entry: tile k's DMA drained (1 phase of flight); phase k-1 LDS visible
        asm volatile("s_waitcnt vmcnt(0)" ::: "memory");
        asm volatile("s_waitcnt lgkmcnt(0)" ::: "memory");
        __builtin_amdgcn_s_barrier();
        __builtin_amdgcn_sched_barrier(0);

        // ---- issue DMA for tile k+1 into the other slot ----
        if (k + 1 < K) {
            char* fd = slot ? fdst0 : fdst1;
            unsigned o0 = off0 > maxoff ? maxoff : off0;
            unsigned o1 = off0 + 8192u; o1 = o1 > maxoff ? maxoff : o1;
            __builtin_amdgcn_global_load_lds((const AS1 float*)((const char*)h + o0),
                                             (AS3 float*)fd, 16, 0, 0);
            __builtin_amdgcn_global_load_lds((const AS1 float*)((const char*)h + o1),
                                             (AS3 float*)(fd + 8192), 16, 0, 0);
            if (wid == 7 && lane < 16) {
                unsigned oy = offy > maxy ? maxy : offy;
                __builtin_amdgcn_global_load_lds((const AS1 int*)((const char*)yhat + oy),
                                                 (AS3 int*)&ylds[slot ^ 1][0], 16, 0, 0);
            }
            off0 += step; offy += ystep;
        }

        // ---- convert(k) and compute(k-1), per-wave order flipped for pipe mixing
        const float* fsb = &fs[slot][0];
        const char*  hsw = (const char*)&hs[slot][0];
        const char*  hsr = (const char*)&hs[slot ^ 1][0];
        const char*  mkw = (const char*)&mk[slot][0];
        const char*  mkr = (const char*)&mk[slot ^ 1][0];

        if (wid & 1) {
            // ---------- convert first ----------
            {
                const float* fp = fsb + (wid * 8) * 64 + lane;
                float x[8];
#pragma unroll
                for (int j = 0; j < 8; ++j) x[j] = fp[j * 64];
                u32x2 lo, hi2;
                lo[0]  = pkh2(0,0); // placeholder overwritten below
                unsigned w0, w1, w2, w3;
                {
                    __hip_bfloat162 p0 = __float22bfloat162_rn(make_float2(x[0], x[1]));
                    __hip_bfloat162 p1 = __float22bfloat162_rn(make_float2(x[2], x[3]));
                    __hip_bfloat162 p2 = __float22bfloat162_rn(make_float2(x[4], x[5]));
                    __hip_bfloat162 p3 = __float22bfloat162_rn(make_float2(x[6], x[7]));
                    __builtin_memcpy(&w0, &p0, 4); __builtin_memcpy(&w1, &p1, 4);
                    __builtin_memcpy(&w2, &p2, 4); __builtin_memcpy(&w3, &p3, 4);
                }
                lo[0] = w0; lo[1] = w1; hi2[0] = w2; hi2[1] = w3;
                char* hb = (char*)hsw + lane * 128 + ((wid * 16) ^ ((lane & 7) << 4));
                *(u32x2*)hb       = lo;
                *(u32x2*)(hb + 8) = hi2;
            }
            if (wid == 7) {
                int y = ylds[slot][lane];
                if (rowN >= N) y = -1;
                unsigned short* mbw = (unsigned short*)mkw;
#pragma unroll
                for (int c = 0; c < NCLS; ++c)
                    mbw[c * TILE + lane] = (y == c) ? (unsigned short)0xFFFFu
                                                    : (unsigned short)0u;
                c0 += (int)__popcll(__ballot(y == 0));
                c1 += (int)__popcll(__ballot(y == 1));
                c2 += (int)__popcll(__ballot(y == 2));
                c3 += (int)__popcll(__ballot(y == 3));
                c4 += (int)__popcll(__ballot(y == 4));
                c5 += (int)__popcll(__ballot(y == 5));
                c6 += (int)__popcll(__ballot(y == 6));
                c7 += (int)__popcll(__ballot(y == 7));
                c8 += (int)__popcll(__ballot(y == 8));
                c9 += (int)__popcll(__ballot(y == 9));
                rowN += G * TILE;
            }
            if (k > 0)
                compute_tile(hsr, mkr, cls, xcls, wq, hi, col, acc, accx);
        } else {
            // ---------- compute first ----------
            if (k > 0)
                compute_tile(hsr, mkr, cls, xcls, wq, hi, col, acc, accx);
            {
                const float* fp = fsb + (wid * 8) * 64 + lane;
                float x[8];
#pragma unroll
                for (int j = 0; j < 8; ++j) x[j] = fp[j * 64];
                unsigned w0, w1, w2, w3;
                {
                    __hip_bfloat162 p0 = __float22bfloat162_rn(make_float2(x[0], x[1]));
                    __hip_bfloat162 p1 = __float22bfloat162_rn(make_float2(x[2], x[3]));
                    __hip_bfloat162 p2 = __float22bfloat162_rn(make_float2(x[4], x[5]));
                    __hip_bfloat162 p3 = __float22bfloat162_rn(make_float2(x[6], x[7]));
                    __builtin_memcpy(&w0, &p0, 4); __builtin_memcpy(&w1, &p1, 4);
                    __builtin_memcpy(&w2, &p2, 4); __builtin_memcpy(&w3, &p3, 4);
                }
                u32x2 lo, hi2;
                lo[0] = w0; lo[1] = w1; hi2[0] = w2; hi2[1] = w3;
                char* hb = (char*)hsw + lane * 128 + ((wid * 16) ^ ((lane & 7) << 4));
                *(u32x2*)hb       = lo;
                *(u32x2*)(hb + 8) = hi2;
            }
        }
    }

    // ---- epilogue: compute the last converted tile ----
    asm volatile("s_waitcnt lgkmcnt(0)" ::: "memory");
    __builtin_amdgcn_s_barrier();
    __builtin_amdgcn_sched_barrier(0);
    compute_tile((const char*)&hs[(K - 1) & 1][0], (const char*)&mk[(K - 1) & 1][0],
                 cls, xcls, wq, hi, col, acc, accx);

    // ---- stream partials (f16) + per-block counts ----
    _Float16* pb = partials + (size_t)bid * PPB;
    {
        _Float16* po = pb + (size_t)cls * (NQ * 256);
#pragma unroll
        for (int q = 0; q < NQ; ++q) {
            u32x2 pk; pk[0] = pkh2(acc[q][0], acc[q][1]);
            pk[1] = pkh2(acc[q][2], acc[q][3]);
            *(u32x2*)(po + q * 256 + (lane << 2)) = pk;
        }
    }
    {
        _Float16* px = pb + (size_t)xcls * (NQ * 256) + (lane << 2);
        u32x2 pk0, pk1, pk2;
        pk0[0] = pkh2(accx[0][0], accx[0][1]); pk0[1] = pkh2(accx[0][2], accx[0][3]);
        pk1[0] = pkh2(accx[1][0], accx[1][1]); pk1[1] = pkh2(accx[1][2], accx[1][3]);
        pk2[0] = pkh2(accx[2][0], accx[2][1]); pk2[1] = pkh2(accx[2][2], accx[2][3]);
        switch (wq) {
        case 0: *(u32x2*)(px + 0 * 256) = pk0;
                *(u32x2*)(px + 1 * 256) = pk1;
                *(u32x2*)(px + 4 * 256) = pk2; break;
        case 1: *(u32x2*)(px + 2 * 256) = pk0;
                *(u32x2*)(px + 3 * 256) = pk1; break;
        case 2: *(u32x2*)(px + 5 * 256) = pk0;
                *(u32x2*)(px + 6 * 256) = pk1;
                *(u32x2*)(px + 7 * 256) = pk2; break;
        default:*(u32x2*)(px + 8 * 256) = pk0;
                *(u32x2*)(px + 9 * 256) = pk1; break;
        }
    }
    if (wid == 7 && lane == 0) {
        int* cp = cntp + bid * 16;
        cp[0]=c0; cp[1]=c1; cp[2]=c2; cp[3]=c3; cp[4]=c4;
        cp[5]=c5; cp[6]=c6; cp[7]=c7; cp[8]=c8; cp[9]=c9;
    }
}

// ---------- kernel 2: chunked block-reduction of f16 partials (atomic-free) ----------
__global__ void HL_reduce(const _Float16* __restrict__ partials, float* __restrict__ rpart,
                          float* __restrict__ out, int G, int CS) {
    const int idx = blockIdx.x * blockDim.x + threadIdx.x;
    if (blockIdx.x == 0 && threadIdx.x == 0) out[0] = 0.f;
    if (idx >= CH * NCLS * NQ * 64) return;
    const int ch = idx / (NCLS * NQ * 64);
    const int r  = idx % (NCLS * NQ * 64);
    const int cq = r >> 6;
    const int l  = r & 63;

    int b0 = ch * CS;
    int b1 = b0 + CS; if (b1 > G) b1 = G;

    f32x4 s = (f32x4){0.f, 0.f, 0.f, 0.f};
    const _Float16* p = partials + (size_t)cq * 256 + (l << 2);
    for (int b = b0; b < b1; ++b) {
        f16x4 v = *(const f16x4*)(p + (size_t)b * PPB);
        s[0] += (float)v[0]; s[1] += (float)v[1];
        s[2] += (float)v[2]; s[3] += (float)v[3];
    }
    *reinterpret_cast<f32x4*>(rpart + ((size_t)ch * (NCLS * NQ) + cq) * 256 + (l << 2)) = s;
}

// ---------- kernel 3: counts + M = 0.5*G/cnt + I; loss += 0.5*logdet ----------
__global__ __launch_bounds__(64, 1) void HL_chol(
        const float* __restrict__ rpart, const int* __restrict__ cntp,
        float* __restrict__ out, int G) {
    __shared__ float M[64][68];
    __shared__ float lcol[64];
    const int cls = blockIdx.x;
    const int i   = threadIdx.x;   // lane 0..63

    int c = 0;
    for (int b = i; b < G; b += 64) c += cntp[b * 16 + cls];
#pragma unroll
    for (int off = 32; off > 0; off >>= 1) c += __shfl_xor(c, off);
    const float inv = 0.5f / (float)c;

    const int QMB[NQ] = {0,0,0,0,1,1,1,2,2,3};
    const int QNB[NQ] = {0,1,2,3,1,2,3,2,3,3};
    const float* rp = rpart + (size_t)cls * (NQ * 256);
#pragma unroll
    for (int q = 0; q < NQ; ++q) {
        f32x4 s = (f32x4){0.f, 0.f, 0.f, 0.f};
#pragma unroll
        for (int ch = 0; ch < CH; ++ch)
            s += *reinterpret_cast<const f32x4*>(rp + (size_t)ch * (NCLS * NQ * 256) + q * 256 + (i << 2));
        const int row0 = QMB[q] * 16 + ((i >> 4) << 2);
        const int colo = QNB[q] * 16 + (i & 15);
#pragma unroll
        for (int rr = 0; rr < 4; ++rr) {
            M[row0 + rr][colo] = s[rr];
            M[colo][row0 + rr] = s[rr];
        }
    }
    __syncthreads();

    float row[64];
#pragma unroll
    for (int c2 = 0; c2 < 64; ++c2)
        row[c2] = M[i][c2] * inv + (c2 == i ? 1.0f : 0.0f);

#pragma unroll
    for (int j = 0; j < 64; ++j) {
        const float piv = __shfl(row[j], j);
        const float li  = row[j] * rsqrtf(piv);
        lcol[i] = li;
        __syncthreads();
#pragma unroll
        for (int c2 = j + 1; c2 < 64; ++c2)
            row[c2] -= li * lcol[c2];
        __syncthreads();
    }

    float slog = 0.f;
#pragma unroll
    for (int j = 0; j < 64; ++j)
        if (i == j) slog = __logf(row[j]);
    slog += __shfl_down(slog, 32); slog += __shfl_down(slog, 16);
    slog += __shfl_down(slog, 8);  slog += __shfl_down(slog, 4);
    slog += __shfl_down(slog, 2);  slog += __shfl_down(slog, 1);
    if (i == 0) atomicAdd(out, 0.5f * slog);
}

// ---------- launcher ----------
extern "C" void kernel_launch(void* const* d_in, const int* in_sizes, int n_in,
                              void* d_out, int out_size, void* d_ws, size_t ws_size,
                              hipStream_t stream) {
    const float* h    = (const float*)d_in[0];
    const int*   yhat = (const int*)d_in[1];
    const int    N    = in_sizes[1];
    float* out = (float*)d_out;

    // ws layout: [rpart CH*100*256 f32][cntp G*16 int][partials G*PPB f16]
    const size_t rpart_sz = (size_t)CH * NCLS * NQ * 256 * sizeof(float);
    const size_t cntp_off = rpart_sz;

    const int ntiles = (N + TILE - 1) / TILE;
    int G = 512;    // 2 blocks per CU
    {
        const size_t perG = 64 + (size_t)PPB * sizeof(_Float16);
        if (ws_size > rpart_sz) {
            size_t maxG = (ws_size - rpart_sz) / perG;
            if ((size_t)G > maxG) G = (int)maxG;
        } else G = 1;
        if (G < 1) G = 1;
    }
    if (G > ntiles) G = ntiles;

    const size_t partials_off = cntp_off + (size_t)G * 16 * sizeof(int);
    float*    rpart    = (float*)d_ws;
    int*      cntp     = (int*)((char*)d_ws + cntp_off);
    _Float16* partials = (_Float16*)((char*)d_ws + partials_off);

    HL_gram<<<G, TPB, 0, stream>>>(h, yhat, partials, cntp, N, ntiles, G);

    int CS = (G + CH - 1) / CH;
    const int rthreads = CH * NCLS * NQ * 64;
    HL_reduce<<<(rthreads + 255) / 256, 256, 0, stream>>>(partials, rpart, out, G, CS);

    HL_chol<<<NCLS, 64, 0, stream>>>(rpart, cntp, out, G);
}